// Round 14
// baseline (305.873 us; speedup 1.0000x reference)
//
#include <hip/hip_runtime.h>
#include <hip/hip_bf16.h>
#include <stdint.h>

#define NTOK 4096
#define DM   512
#define HD   2048
#define NE   8

typedef __bf16 bf16x8 __attribute__((ext_vector_type(8)));
typedef float  f32x4  __attribute__((ext_vector_type(4)));

__device__ __forceinline__ unsigned short f2bf(float f) {
  unsigned int u = __float_as_uint(f);
  u += 0x7FFF + ((u >> 16) & 1);   // RTNE
  return (unsigned short)(u >> 16);
}

__device__ __forceinline__ float gelu_fast(float x) {
  float s = 1.5957691216f * (x + 0.044715f * x * x * x);
  return x / (1.f + __expf(-s));
}

// ---------- W[e][K][N] fp32 -> WT[e][N][K] bf16 transpose (device body) ----------
template<int K, int N>
__device__ __forceinline__ void transw_dev(
    const float* __restrict__ in, unsigned short* __restrict__ out,
    int bid, int t, float (*tile)[33]) {
  const int tpe = (K / 32) * (N / 32);
  int e   = bid / tpe;
  int rem = bid % tpe;
  int kt  = rem / (N / 32), nt = rem % (N / 32);
  int tx  = t & 31, ty = t >> 5;
  const float* src = in + ((size_t)e * K + kt * 32) * N + (size_t)nt * 32;
  #pragma unroll
  for (int i = 0; i < 4; i++) {
    int r = ty + i * 8;
    tile[r][tx] = src[(size_t)r * N + tx];
  }
  __syncthreads();
  unsigned short* dst = out + ((size_t)e * N + nt * 32) * K + (size_t)kt * 32;
  #pragma unroll
  for (int i = 0; i < 4; i++) {
    int rr = ty + i * 8;
    dst[(size_t)rr * K + tx] = f2bf(tile[tx][rr]);
  }
}

// ---------- fused prep: transw1 | transw2 | gate ----------
// [0,8192) w1 transpose | [8192,16384) w2 transpose | [16384,17408) gate
__global__ __launch_bounds__(256) void prep_kernel(
    const float* __restrict__ inp, const float* __restrict__ w1,
    const float* __restrict__ w2, const float* __restrict__ gw,
    const float* __restrict__ gb, unsigned short* __restrict__ W1T,
    unsigned short* __restrict__ W2T, int* __restrict__ eidx,
    float* __restrict__ wgtA) {
  __shared__ float tile[32][33];
  const int b = blockIdx.x;
  const int t = threadIdx.x;

  if (b < 8192) {                     // ---- transpose w1 [8][512][2048] -> [8][2048][512]
    transw_dev<DM, HD>(w1, W1T, b, t, tile);
  } else if (b < 16384) {             // ---- transpose w2 [8][2048][512] -> [8][512][2048]
    transw_dev<HD, DM>(w2, W2T, b - 8192, t, tile);
  } else {                            // ---- gate
    int tok = (b - 16384) * 4 + (t >> 6);
    int l   = t & 63;
    const float* x = inp + (size_t)tok * DM;
    float acc[NE];
    #pragma unroll
    for (int e = 0; e < NE; e++) acc[e] = 0.f;
    #pragma unroll
    for (int j = 0; j < DM / 64; j++) {
      int d = j * 64 + l;
      float xv = x[d];
      const float* g = gw + (size_t)d * NE;
      #pragma unroll
      for (int e = 0; e < NE; e++) acc[e] += xv * g[e];
    }
    #pragma unroll
    for (int off = 32; off >= 1; off >>= 1) {
      #pragma unroll
      for (int e = 0; e < NE; e++) acc[e] += __shfl_xor(acc[e], off, 64);
    }
    if (l == 0) {
      float lg[NE];
      #pragma unroll
      for (int e = 0; e < NE; e++) lg[e] = acc[e] + gb[e];
      int i0 = 0;
      #pragma unroll
      for (int e = 1; e < NE; e++) if (lg[e] > lg[i0]) i0 = e;
      int i1 = (i0 == 0) ? 1 : 0;
      #pragma unroll
      for (int e = 0; e < NE; e++) if (e != i0 && lg[e] > lg[i1]) i1 = e;
      float ev = expf(lg[i1] - lg[i0]);
      float w0 = 1.f / (1.f + ev);
      float w1s = ev * w0;
      wgtA[tok * 2]     = w0;
      wgtA[tok * 2 + 1] = w1s;
      eidx[tok * 2]     = i0;
      eidx[tok * 2 + 1] = i1;
    }
  }
}

// ---------- build per-expert entry lists ----------
__global__ __launch_bounds__(256) void build_lists(
    const int* __restrict__ eidx, int* __restrict__ lists,
    int* __restrict__ counts) {
  __shared__ int wsums[4];
  __shared__ int base;
  const int e = blockIdx.x;
  const int t = threadIdx.x;
  const int lane = t & 63, w = t >> 6;
  if (t == 0) base = 0;
  __syncthreads();
  for (int it = 0; it < 2 * NTOK / 256; ++it) {
    int i = it * 256 + t;
    int match = (eidx[i] == e) ? 1 : 0;
    unsigned long long b = __ballot(match);
    int wsum = __popcll(b);
    int lpre = __popcll(b & ((1ull << lane) - 1ull));
    if (lane == 0) wsums[w] = wsum;
    __syncthreads();
    int wpre = 0;
    #pragma unroll
    for (int k = 0; k < 4; k++) if (k < w) wpre += wsums[k];
    int tot = wsums[0] + wsums[1] + wsums[2] + wsums[3];
    if (match) lists[e * NTOK + base + wpre + lpre] = i;
    __syncthreads();
    if (t == 0) base += tot;
    __syncthreads();
  }
  if (t == 0) counts[e] = base;
}

// ---------- gatherX: expert-sorted X (fp32 -> bf16) + sortidx (R7-verified) ----------
__global__ __launch_bounds__(512) void gatherX(
    const float* __restrict__ inp, const int* __restrict__ lists,
    const int* __restrict__ counts, unsigned short* __restrict__ Xg,
    int* __restrict__ sortidx) {
  const int b = blockIdx.x;
  const int e = b >> 5, lt = b & 31;
  const int cnt = counts[e];
  int off = 0;
  #pragma unroll
  for (int i = 0; i < NE; i++) if (i < e) off += counts[i];
  const int t = threadIdx.x;
  const int r = t >> 2, q = t & 3;
  const int local = lt * 128 + r;
  if (local >= cnt) return;
  const int entry = lists[e * NTOK + local];
  const int tok = entry >> 1;
  const int gpos = off + local;
  if (q == 0) sortidx[gpos] = entry;
  const float* src = inp + (size_t)tok * DM + q * 128;
  unsigned short* dst = Xg + (size_t)gpos * DM + q * 128;
  #pragma unroll
  for (int j = 0; j < 16; j++) {
    f32x4 v0 = ((const f32x4*)src)[2 * j], v1 = ((const f32x4*)src)[2 * j + 1];
    union { unsigned short s[8]; uint4 u; } o;
    #pragma unroll
    for (int k = 0; k < 4; k++) { o.s[k] = f2bf(v0[k]); o.s[4 + k] = f2bf(v1[k]); }
    ((uint4*)dst)[j] = o.u;
  }
}

// ---------- W-stationary A-streaming GEMM (R13 ablation: staging path was 100% of time;
// this removes ALL hot-loop barriers). Block: 64-col x 512-K W panel in LDS (staged once,
// XOR-swizzled); 8 waves stream sorted A rows through REGISTERS (plain global loads,
// compiler-pipelined s_waitcnt, no __syncthreads). KW=512, COLS=64 both layers.
// L1: KSPLIT=1 (K=512), write Hs sorted. L2: KSPLIT=4 (K-window 512), atomicAdd via sortidx.
template<int KDIM, int NDIM, bool IS_L1, int KSPLIT>
__global__ __launch_bounds__(512) void moe_stream(
    const unsigned short* __restrict__ A,      // [8192][KDIM] bf16 sorted rows
    const unsigned short* __restrict__ WT,     // [E][NDIM][KDIM] bf16
    const float* __restrict__ bias,            // [E][NDIM]
    const int* __restrict__ counts,            // [E]
    const float* __restrict__ wgtA,            // [2*NTOK]
    const int* __restrict__ sortidx,           // [8192]
    unsigned short* __restrict__ Hout,
    float* __restrict__ Out) {
  __shared__ char lds_w[65536];                // 64 cols x 512 K bf16, swizzled

  const int CT  = NDIM / 64;
  const int e   = blockIdx.x & 7;              // expert == XCD
  const int sub = blockIdx.x >> 3;
  const int ct  = sub % CT;
  const int ks  = sub / CT;                    // 0 for L1; 0..3 for L2

  int off = 0, cnt = 0;
  #pragma unroll
  for (int i = 0; i < NE; i++) {
    int c = counts[i];
    if (i < e) off += c;
    if (i == e) cnt = c;
  }

  const int t = threadIdx.x;
  // ---- stage W panel once: thread t -> col=t>>3, k-quarter=(t&7)*64 elems, 8x16B
  {
    const int col = t >> 3;
    const int kq  = t & 7;
    const unsigned short* wsrc =
        WT + ((long)e * NDIM + ct * 64 + col) * KDIM + ks * 512 + kq * 64;
    #pragma unroll
    for (int j = 0; j < 8; ++j) {
      uint4 v = *(const uint4*)(wsrc + j * 8);
      int kb = (kq * 128 + j * 16) ^ ((col & 7) << 4);
      *(uint4*)&lds_w[col * 1024 + kb] = v;
    }
  }
  __syncthreads();                             // the ONLY barrier

  const int lane = t & 63;
  const int wv   = t >> 6;                     // 0..7
  const int l15  = lane & 15;
  const int ksub = lane >> 4;                  // 0..3

  float bv[4];
  #pragma unroll
  for (int c = 0; c < 4; ++c)
    bv[c] = (KSPLIT == 1 || ks == 0) ? bias[e * NDIM + ct * 64 + c * 16 + l15] : 0.f;

  const unsigned short* Abase = A + (long)off * KDIM + ks * 512;

  // ---- stream rows: wave wv handles 32-row chunks at rbase = wv*32 + it*256
  for (int rbase = wv * 32; rbase < cnt; rbase += 256) {
    int r0 = rbase + l15;       r0 = r0 < cnt ? r0 : cnt - 1;
    int r1 = rbase + 16 + l15;  r1 = r1 < cnt ? r1 : cnt - 1;
    const unsigned short* pA0 = Abase + (long)r0 * KDIM;
    const unsigned short* pA1 = Abase + (long)r1 * KDIM;

    f32x4 acc[4][2] = {};
    #pragma unroll
    for (int k = 0; k < 16; ++k) {
      int koff = k * 32 + ksub * 8;
      bf16x8 a0 = *(const bf16x8*)(pA0 + koff);
      bf16x8 a1 = *(const bf16x8*)(pA1 + koff);
      #pragma unroll
      for (int c = 0; c < 4; ++c) {
        int col = c * 16 + l15;
        int kb  = (koff * 2) ^ ((col & 7) << 4);
        bf16x8 bf = *(const bf16x8*)&lds_w[col * 1024 + kb];
        acc[c][0] = __builtin_amdgcn_mfma_f32_16x16x32_bf16(a0, bf, acc[c][0], 0, 0, 0);
        acc[c][1] = __builtin_amdgcn_mfma_f32_16x16x32_bf16(a1, bf, acc[c][1], 0, 0, 0);
      }
    }

    // epilogue per chunk: C/D col=lane&15, row=(lane>>4)*4+reg (m89)
    #pragma unroll
    for (int c = 0; c < 4; ++c) {
      int col = ct * 64 + c * 16 + l15;
      #pragma unroll
      for (int h = 0; h < 2; ++h) {
        #pragma unroll
        for (int r = 0; r < 4; ++r) {
          int row = rbase + h * 16 + ksub * 4 + r;
          if (row >= cnt) continue;
          float v = acc[c][h][r] + bv[c];
          if (IS_L1) {
            Hout[(size_t)(off + row) * NDIM + col] = f2bf(gelu_fast(v));
          } else {
            int ent = sortidx[off + row];
            atomicAdd(Out + (size_t)(ent >> 1) * NDIM + col, v * wgtA[ent]);
          }
        }
      }
    }
  }
}

extern "C" void kernel_launch(void* const* d_in, const int* in_sizes, int n_in,
                              void* d_out, int out_size, void* d_ws, size_t ws_size,
                              hipStream_t stream) {
  const float* inp = (const float*)d_in[0];
  const float* gw  = (const float*)d_in[1];
  const float* gb  = (const float*)d_in[2];
  const float* w1  = (const float*)d_in[3];
  const float* b1  = (const float*)d_in[4];
  const float* w2  = (const float*)d_in[5];
  const float* b2  = (const float*)d_in[6];
  float* out = (float*)d_out;

  char* ws = (char*)d_ws;
  unsigned short* W1T  = (unsigned short*)(ws + 0);          // 16 MiB [8][2048][512]
  unsigned short* W2T  = (unsigned short*)(ws + 16777216);   // 16 MiB [8][512][2048]
  unsigned short* Xg   = (unsigned short*)(ws + 33554432);   //  8 MiB [8192][512] sorted
  unsigned short* Hs   = (unsigned short*)(ws + 41943040);   // 32 MiB [8192][2048] sorted
  int*   lists   = (int*)  (ws + 75497472);                  // [8][4096]
  float* wgtA    = (float*)(ws + 75628544);                  // [8192]
  int*   eidx    = (int*)  (ws + 75661312);                  // [8192]
  int*   sortidx = (int*)  (ws + 75694080);                  // [8192]
  int*   counts  = (int*)  (ws + 75726848);                  // [8]

  hipMemsetAsync(out, 0, (size_t)NTOK * DM * sizeof(float), stream);

  prep_kernel<<<17408, 256, 0, stream>>>(inp, w1, w2, gw, gb,
                                         W1T, W2T, eidx, wgtA);
  build_lists<<<NE, 256, 0, stream>>>(eidx, lists, counts);
  gatherX<<<NE * 32, 512, 0, stream>>>(inp, lists, counts, Xg, sortidx);
  // L1: 8 experts x 32 col-tiles = 256 blocks, K=512 whole
  moe_stream<DM, HD, true, 1><<<8 * (HD / 64) * 1, 512, 0, stream>>>(
      Xg, W1T, b1, counts, wgtA, sortidx, Hs, nullptr);
  // L2: 8 experts x 8 col-tiles x 4 K-windows = 256 blocks
  moe_stream<HD, DM, false, 4><<<8 * (DM / 64) * 4, 512, 0, stream>>>(
      Hs, W2T, b2, counts, wgtA, sortidx, nullptr, out);
}

// Round 15
// 160.437 us; speedup vs baseline: 1.9065x; 1.9065x over previous
//
#include <hip/hip_runtime.h>
#include <hip/hip_bf16.h>
#include <stdint.h>

#define NTOK 4096
#define DM   512
#define HD   2048
#define NE   8

typedef __bf16 bf16x8 __attribute__((ext_vector_type(8)));
typedef float  f32x4  __attribute__((ext_vector_type(4)));

__device__ __forceinline__ unsigned short f2bf(float f) {
  unsigned int u = __float_as_uint(f);
  u += 0x7FFF + ((u >> 16) & 1);   // RTNE
  return (unsigned short)(u >> 16);
}

__device__ __forceinline__ float gelu_fast(float x) {
  float s = 1.5957691216f * (x + 0.044715f * x * x * x);
  return x / (1.f + __expf(-s));
}

__device__ __forceinline__ void gload_lds16(const void* g, void* l) {
  __builtin_amdgcn_global_load_lds(
      (__attribute__((address_space(1))) const void*)g,
      (__attribute__((address_space(3))) void*)l,
      16, 0, 0);
}

// ---------- W[e][K][N] fp32 -> WT[e][N][K] bf16 transpose (device body) ----------
template<int K, int N>
__device__ __forceinline__ void transw_dev(
    const float* __restrict__ in, unsigned short* __restrict__ out,
    int bid, int t, float (*tile)[33]) {
  const int tpe = (K / 32) * (N / 32);
  int e   = bid / tpe;
  int rem = bid % tpe;
  int kt  = rem / (N / 32), nt = rem % (N / 32);
  int tx  = t & 31, ty = t >> 5;
  const float* src = in + ((size_t)e * K + kt * 32) * N + (size_t)nt * 32;
  #pragma unroll
  for (int i = 0; i < 4; i++) {
    int r = ty + i * 8;
    tile[r][tx] = src[(size_t)r * N + tx];
  }
  __syncthreads();
  unsigned short* dst = out + ((size_t)e * N + nt * 32) * K + (size_t)kt * 32;
  #pragma unroll
  for (int i = 0; i < 4; i++) {
    int rr = ty + i * 8;
    dst[(size_t)rr * K + tx] = f2bf(tile[tx][rr]);
  }
}

// ---------- fused prep: convx | transw1 | transw2 | gate ----------
// [0,1024) convx | [1024,9216) transw1 | [9216,17408) transw2 | [17408,18432) gate
__global__ __launch_bounds__(256) void prep_kernel(
    const float* __restrict__ inp, const float* __restrict__ w1,
    const float* __restrict__ w2, const float* __restrict__ gw,
    const float* __restrict__ gb, unsigned short* __restrict__ Xb,
    unsigned short* __restrict__ W1T, unsigned short* __restrict__ W2T,
    int* __restrict__ eidx, float* __restrict__ wgtA) {
  __shared__ float tile[32][33];
  const int b = blockIdx.x;
  const int t = threadIdx.x;

  if (b < 1024) {                     // ---- convx
    int i = b * 256 + t;
    const f32x4* p = (const f32x4*)(inp + (size_t)i * 8);
    f32x4 v0 = p[0], v1 = p[1];
    union { unsigned short s[8]; uint4 u; } o;
    #pragma unroll
    for (int j = 0; j < 4; j++) { o.s[j] = f2bf(v0[j]); o.s[4 + j] = f2bf(v1[j]); }
    *(uint4*)(Xb + (size_t)i * 8) = o.u;
  } else if (b < 9216) {              // ---- transpose w1
    transw_dev<DM, HD>(w1, W1T, b - 1024, t, tile);
  } else if (b < 17408) {             // ---- transpose w2
    transw_dev<HD, DM>(w2, W2T, b - 9216, t, tile);
  } else {                            // ---- gate
    int tok = (b - 17408) * 4 + (t >> 6);
    int l   = t & 63;
    const float* x = inp + (size_t)tok * DM;
    float acc[NE];
    #pragma unroll
    for (int e = 0; e < NE; e++) acc[e] = 0.f;
    #pragma unroll
    for (int j = 0; j < DM / 64; j++) {
      int d = j * 64 + l;
      float xv = x[d];
      const float* g = gw + (size_t)d * NE;
      #pragma unroll
      for (int e = 0; e < NE; e++) acc[e] += xv * g[e];
    }
    #pragma unroll
    for (int off = 32; off >= 1; off >>= 1) {
      #pragma unroll
      for (int e = 0; e < NE; e++) acc[e] += __shfl_xor(acc[e], off, 64);
    }
    if (l == 0) {
      float lg[NE];
      #pragma unroll
      for (int e = 0; e < NE; e++) lg[e] = acc[e] + gb[e];
      int i0 = 0;
      #pragma unroll
      for (int e = 1; e < NE; e++) if (lg[e] > lg[i0]) i0 = e;
      int i1 = (i0 == 0) ? 1 : 0;
      #pragma unroll
      for (int e = 0; e < NE; e++) if (e != i0 && lg[e] > lg[i1]) i1 = e;
      float ev = expf(lg[i1] - lg[i0]);
      float w0 = 1.f / (1.f + ev);
      float w1s = ev * w0;
      wgtA[tok * 2]     = w0;
      wgtA[tok * 2 + 1] = w1s;
      eidx[tok * 2]     = i0;
      eidx[tok * 2 + 1] = i1;
    }
  }
}

// ---------- build per-expert entry lists ----------
__global__ __launch_bounds__(256) void build_lists(
    const int* __restrict__ eidx, int* __restrict__ lists,
    int* __restrict__ counts) {
  __shared__ int wsums[4];
  __shared__ int base;
  const int e = blockIdx.x;
  const int t = threadIdx.x;
  const int lane = t & 63, w = t >> 6;
  if (t == 0) base = 0;
  __syncthreads();
  for (int it = 0; it < 2 * NTOK / 256; ++it) {
    int i = it * 256 + t;
    int match = (eidx[i] == e) ? 1 : 0;
    unsigned long long b = __ballot(match);
    int wsum = __popcll(b);
    int lpre = __popcll(b & ((1ull << lane) - 1ull));
    if (lane == 0) wsums[w] = wsum;
    __syncthreads();
    int wpre = 0;
    #pragma unroll
    for (int k = 0; k < 4; k++) if (k < w) wpre += wsums[k];
    int tot = wsums[0] + wsums[1] + wsums[2] + wsums[3];
    if (match) lists[e * NTOK + base + wpre + lpre] = i;
    __syncthreads();
    if (t == 0) base += tot;
    __syncthreads();
  }
  if (t == 0) counts[e] = base;
}

// ---------- gathered GEMM: 128x128 tile, BK=64, 4 waves, counted-vmcnt dbuf ----------
// T3/T4 recipe done correctly (vs R6's broken version): STAGE next tile BEFORE
// waiting; s_waitcnt vmcnt(8) waits ONLY the current tile (next tile's 8 loads
// stay in flight across the barrier, covered by compute); barrier AFTER the
// counted wait; NO sched_barrier (m141), NO manual lgkmcnt (compiler handles
// ds_read waits). Buffer reuse protected by the post-compute barrier.
template<int KDIM, int NDIM, bool IS_L1>
__global__ __launch_bounds__(256) void moe_gemm(
    const unsigned short* __restrict__ A,
    const unsigned short* __restrict__ WT,     // [E][NDIM][KDIM] bf16
    const float* __restrict__ bias,            // [E][NDIM]
    const int* __restrict__ lists,             // [E][NTOK]
    const int* __restrict__ counts,            // [E]
    const float* __restrict__ wgtA,            // [2*NTOK]
    unsigned short* __restrict__ Hout,
    float* __restrict__ Out) {
  __shared__ unsigned short ldsA0[128 * 64];   // 16 KiB each, 64 KiB total
  __shared__ unsigned short ldsB0[128 * 64];
  __shared__ unsigned short ldsA1[128 * 64];
  __shared__ unsigned short ldsB1[128 * 64];
  __shared__ int ldsE[128];

  const int CT  = NDIM / 128;
  const int e   = blockIdx.x & 7;              // expert == XCD (R10: FETCH 35->20MB)
  const int idx = blockIdx.x >> 3;
  const int rt  = idx / CT;
  const int ct  = idx % CT;
  const int cnt = counts[e];
  if (rt * 128 >= cnt) return;

  const int t = threadIdx.x;
  if (t < 128) {
    int rg = rt * 128 + t;
    ldsE[t] = lists[e * NTOK + (rg < cnt ? rg : cnt - 1)];
  }
  __syncthreads();

  const int lane = t & 63;
  const int wid  = t >> 6;
  const int wr = wid >> 1, wc = wid & 1;
  const int rowsel = t >> 3;                   // 0..31 (R5-verified BK=64 staging)
  const int colsel = (t & 7) ^ (rowsel & 7);   // inverse-swizzled 16B source chunk

  const unsigned short* aptr[4];
  const unsigned short* bptr[4];
  #pragma unroll
  for (int i = 0; i < 4; i++) {
    int rl = i * 32 + rowsel;
    int entry = ldsE[rl];
    long arow = IS_L1 ? (entry >> 1) : entry;
    aptr[i] = A + arow * (long)KDIM + colsel * 8;
    bptr[i] = WT + ((long)e * NDIM + ct * 128 + rl) * KDIM + colsel * 8;
  }

  f32x4 acc[4][4] = {};
  const int NKT = KDIM / 64;                   // 8 (L1) or 32 (L2), power of 2

  // 4 A-loads + 4 B-loads per thread = 8 VMEM per wave-lane per tile
  #define STAGE(LA, LB, KT) do {                                              \
    const int _off = (KT) * 64;                                               \
    _Pragma("unroll")                                                         \
    for (int i = 0; i < 4; i++) {                                             \
      gload_lds16(aptr[i] + _off, (char*)(LA) + i * 4096 + wid * 1024);       \
      gload_lds16(bptr[i] + _off, (char*)(LB) + i * 4096 + wid * 1024);       \
    }                                                                         \
  } while (0)

  #define COMPUTE(LA, LB) do {                                                \
    _Pragma("unroll")                                                         \
    for (int kk = 0; kk < 2; ++kk) {                                          \
      bf16x8 a[4], b[4];                                                      \
      int ko = kk * 32 + (lane >> 4) * 8;                                     \
      _Pragma("unroll")                                                       \
      for (int m = 0; m < 4; m++) {                                           \
        int ra = wr * 64 + m * 16 + (lane & 15);                              \
        a[m] = *(const bf16x8*)&(LA)[ra * 64 + (ko ^ ((ra & 7) << 3))];       \
      }                                                                       \
      _Pragma("unroll")                                                       \
      for (int n = 0; n < 4; n++) {                                           \
        int rb = wc * 64 + n * 16 + (lane & 15);                              \
        b[n] = *(const bf16x8*)&(LB)[rb * 64 + (ko ^ ((rb & 7) << 3))];       \
      }                                                                       \
      _Pragma("unroll")                                                       \
      for (int m = 0; m < 4; m++)                                             \
        _Pragma("unroll")                                                     \
        for (int n = 0; n < 4; n++)                                           \
          acc[m][n] = __builtin_amdgcn_mfma_f32_16x16x32_bf16(                \
              a[m], b[n], acc[m][n], 0, 0, 0);                                \
    }                                                                         \
  } while (0)

  // PIPE: issue next tile's loads, wait only CURRENT tile (8 of 16 outstanding
  // retire in issue order), sync, compute, sync (releases buffer for reuse).
  // Last iteration wraps the dummy stage to tile 0 (never read; keeps vmcnt math
  // uniform) into the buffer NOT being computed.
  #define PIPE(CA, CB, NA, NB, KT) do {                                       \
    STAGE(NA, NB, ((KT) + 1) & (NKT - 1));                                    \
    asm volatile("s_waitcnt vmcnt(8)" ::: "memory");                          \
    __builtin_amdgcn_s_barrier();                                             \
    COMPUTE(CA, CB);                                                          \
    __builtin_amdgcn_s_barrier();                                             \
  } while (0)

  STAGE(ldsA0, ldsB0, 0);                      // prologue: 8 in flight
  for (int kt = 0; kt < NKT; kt += 2) {
    PIPE(ldsA0, ldsB0, ldsA1, ldsB1, kt);
    PIPE(ldsA1, ldsB1, ldsA0, ldsB0, kt + 1);
  }
  asm volatile("s_waitcnt vmcnt(0)" ::: "memory");  // drain dummy before endpgm
  #undef STAGE
  #undef COMPUTE
  #undef PIPE

  // epilogue: C/D mapping col=lane&15, row=(lane>>4)*4+reg (m89-verified)
  #pragma unroll
  for (int m = 0; m < 4; m++) {
    int rbase = wr * 64 + m * 16 + (lane >> 4) * 4;
    int ent[4];
    #pragma unroll
    for (int r = 0; r < 4; r++) ent[r] = ldsE[rbase + r];
    #pragma unroll
    for (int n = 0; n < 4; n++) {
      int col = ct * 128 + wc * 64 + n * 16 + (lane & 15);
      float bv = bias[e * NDIM + col];
      #pragma unroll
      for (int r = 0; r < 4; r++) {
        if (rt * 128 + rbase + r >= cnt) continue;
        float v = acc[m][n][r] + bv;
        if (IS_L1) {
          Hout[(size_t)ent[r] * NDIM + col] = f2bf(gelu_fast(v));
        } else {
          atomicAdd(Out + (size_t)(ent[r] >> 1) * NDIM + col, v * wgtA[ent[r]]);
        }
      }
    }
  }
}

extern "C" void kernel_launch(void* const* d_in, const int* in_sizes, int n_in,
                              void* d_out, int out_size, void* d_ws, size_t ws_size,
                              hipStream_t stream) {
  const float* inp = (const float*)d_in[0];
  const float* gw  = (const float*)d_in[1];
  const float* gb  = (const float*)d_in[2];
  const float* w1  = (const float*)d_in[3];
  const float* b1  = (const float*)d_in[4];
  const float* w2  = (const float*)d_in[5];
  const float* b2  = (const float*)d_in[6];
  float* out = (float*)d_out;

  char* ws = (char*)d_ws;
  unsigned short* Xb   = (unsigned short*)(ws + 0);          //  4 MiB
  unsigned short* W1T  = (unsigned short*)(ws + 4194304);    // 16 MiB
  unsigned short* W2T  = (unsigned short*)(ws + 20971520);   // 16 MiB
  unsigned short* Hbuf = (unsigned short*)(ws + 37748736);   // 32 MiB
  int*   lists  = (int*)  (ws + 71303168);                   // [8][4096]
  float* wgtA   = (float*)(ws + 71434240);                   // [8192]
  int*   counts = (int*)  (ws + 71467008);                   // [8]
  int*   eidx   = (int*)  (ws + 71467072);                   // [8192]

  hipMemsetAsync(out, 0, (size_t)NTOK * DM * sizeof(float), stream);

  prep_kernel<<<18432, 256, 0, stream>>>(inp, w1, w2, gw, gb,
                                         Xb, W1T, W2T, eidx, wgtA);
  build_lists<<<NE, 256, 0, stream>>>(eidx, lists, counts);
  moe_gemm<DM, HD, true ><<<8 * 32 * (HD / 128), 256, 0, stream>>>(
      Xb, W1T, b1, lists, counts, wgtA, Hbuf, nullptr);
  moe_gemm<HD, DM, false><<<8 * 32 * (DM / 128), 256, 0, stream>>>(
      Hbuf, W2T, b2, lists, counts, wgtA, nullptr, out);
}